// Round 22
// baseline (141.790 us; speedup 1.0000x reference)
//
#include <hip/hip_runtime.h>
#include <hip/hip_bf16.h>
#include <cstdint>

#define BB 2
#define SS 2048
#define DD 1024
#define HH 16
#define DK 64
#define MROWS (BB*SS)        // 4096
#define NQKV  (3*DD)         // 3072

typedef __bf16 bf16x8 __attribute__((ext_vector_type(8)));
typedef float  f32x4  __attribute__((ext_vector_type(4)));
typedef float  f32x16 __attribute__((ext_vector_type(16)));
typedef unsigned u32x2 __attribute__((ext_vector_type(2)));

static __device__ __forceinline__ unsigned short f2bf(float f) {
    __bf16 h = (__bf16)f;
    return __builtin_bit_cast(unsigned short, h);
}
static __device__ __forceinline__ float bf2f(unsigned short u) {
    return (float)__builtin_bit_cast(__bf16, u);
}

#define GLOAD16(gsrc, ldst) \
    __builtin_amdgcn_global_load_lds((const __attribute__((address_space(1))) void*)(gsrc), \
                                     (__attribute__((address_space(3))) void*)(ldst), 16, 0, 0)

// v_permlane32_swap_b32: first operand's HIGH half swaps with second operand's LOW half.
static __device__ __forceinline__ void pl32_swap(unsigned &x, unsigned &y) {
#if __has_builtin(__builtin_amdgcn_permlane32_swap)
    u32x2 r = __builtin_amdgcn_permlane32_swap(x, y, false, false);
    x = r[0]; y = r[1];
#else
    asm volatile("v_permlane32_swap_b32 %0, %1" : "+v"(x), "+v"(y));
#endif
}
static __device__ __forceinline__ float swap_half(float v, bool hi) {
    unsigned x = __builtin_bit_cast(unsigned, v), y = x;
    pl32_swap(x, y);
    return __builtin_bit_cast(float, hi ? x : y);
}
// T12: build PV B-frag from 8 f32 C-layout regs (verified R10).
template<int BASE> static __device__ __forceinline__ bf16x8 cvt_chunk(const f32x16 &p) {
    unsigned x0, y0, x1, y1;
    asm("v_cvt_pk_bf16_f32 %0, %1, %2" : "=v"(x0) : "v"(p[BASE+0]), "v"(p[BASE+1]));
    asm("v_cvt_pk_bf16_f32 %0, %1, %2" : "=v"(y0) : "v"(p[BASE+4]), "v"(p[BASE+5]));
    asm("v_cvt_pk_bf16_f32 %0, %1, %2" : "=v"(x1) : "v"(p[BASE+2]), "v"(p[BASE+3]));
    asm("v_cvt_pk_bf16_f32 %0, %1, %2" : "=v"(y1) : "v"(p[BASE+6]), "v"(p[BASE+7]));
    pl32_swap(x0, y0);
    pl32_swap(x1, y1);
    union { unsigned u[4]; bf16x8 v; } r;
    r.u[0] = x0; r.u[1] = x1; r.u[2] = y0; r.u[3] = y1;
    return r.v;
}

// ---------------------------------------------------------------- cast x + weights to bf16
__global__ void cast_all(const float* __restrict__ x,  const float* __restrict__ wq,
                         const float* __restrict__ wk, const float* __restrict__ wv,
                         const float* __restrict__ wo,
                         unsigned short* __restrict__ xb, unsigned short* __restrict__ wqkv,
                         unsigned short* __restrict__ wob)
{
    const int NX = MROWS * DD;      // 4194304
    const int NW = DD * DD;         // 1048576
    const int total = (NX + 4 * NW) / 8;
    for (int i = blockIdx.x * blockDim.x + threadIdx.x; i < total; i += gridDim.x * blockDim.x) {
        int base = i * 8;
        const float* src; unsigned short* dst; int off;
        if      (base < NX)          { src = x;  dst = xb;          off = base; }
        else if (base < NX + NW)     { src = wq; dst = wqkv;        off = base - NX; }
        else if (base < NX + 2*NW)   { src = wk; dst = wqkv + NW;   off = base - NX - NW; }
        else if (base < NX + 3*NW)   { src = wv; dst = wqkv + 2*NW; off = base - NX - 2*NW; }
        else                         { src = wo; dst = wob;         off = base - NX - 3*NW; }
        float4 a = *(const float4*)(src + off);
        float4 b = *(const float4*)(src + off + 4);
        union { unsigned short s[8]; uint4 v; } u;
        u.s[0] = f2bf(a.x); u.s[1] = f2bf(a.y); u.s[2] = f2bf(a.z); u.s[3] = f2bf(a.w);
        u.s[4] = f2bf(b.x); u.s[5] = f2bf(b.y); u.s[6] = f2bf(b.z); u.s[7] = f2bf(b.w);
        *(uint4*)(dst + off) = u.v;
    }
}

// ---------------------------------------------------------------- RoPE cos/sin table [2048][32]
__global__ void rope_table(float* __restrict__ tabc, float* __restrict__ tabs)
{
    int i = blockIdx.x * blockDim.x + threadIdx.x;   // 65536 threads
    int s = i >> 5, d = i & 31;
    float inv = exp2f(-(float)d * (13.287712379549449f / 32.f));  // 10000^(-d/32)
    float ang = (float)s * inv;
    tabc[i] = cosf(ang);
    tabs[i] = sinf(ang);
}

// ---------------------------------------------------------------- fused QKV GEMM + RoPE epilogue
// 256x256, 8 waves (2Mx4N), T4 counted-vmcnt pipeline: K split into 32-wide k-halves,
// 4 LDS slots per matrix (4 x [256][32] = 64KB each, 128KB total), 2-3 k-halves in
// flight. Per phase: s_waitcnt vmcnt(4) (own older loads confirmed; in-order retire)
// -> s_barrier (collective confirm + slot-reuse gate) -> issue kh n+3 (4 loads) into
// slot (n-1)&3 -> 12 ds_read_b128 -> 32 MFMA (setprio). Never vmcnt(0) except final
// phase (tail). Chunk-XOR swizzle ch^=row&3 via pre-swizzled global source.
__global__ __launch_bounds__(512) void gemm_qkv(
    const unsigned short* __restrict__ A, const unsigned short* __restrict__ Bm,
    const int* __restrict__ pids,
    const float* __restrict__ tabc, const float* __restrict__ tabs,
    unsigned short* __restrict__ Qb, unsigned short* __restrict__ Kb,
    unsigned short* __restrict__ Vr)
{
    __shared__ __align__(16) unsigned short sA[4][8192];   // 4 k-half slots [256][32]
    __shared__ __align__(16) unsigned short sB[4][8192];
    const int tid = threadIdx.x;
    const int w = tid >> 6, l = tid & 63;
    const int wm = w >> 2, wn = w & 3;       // 2M x 4N wave grid
    const int lr = l & 15, lg = l >> 4;
    // XCD swizzle: 192 blocks = 8 XCDs x 24 (bijective)
    const int swz = (blockIdx.x & 7) * 24 + (blockIdx.x >> 3);
    const int bx = swz % 12, by = swz / 12;
    const int mBase = by * 256;
    const int nBase = bx * 256;
    const int srow = tid >> 2;               // 0..127 staging row within round
    const int schw = tid & 3;                // staging chunk-word

    f32x4 acc[8][4] = {};

    // stage k-half kh (0..31) into slot kh&3; 4 loads/thread (2 rounds x A,B)
    auto stage = [&](int kh) {
        const int slot = kh & 3;
        const int kbase = (kh >> 1) * 64 + (kh & 1) * 32;
        #pragma unroll
        for (int r = 0; r < 2; ++r) {
            int row = r * 128 + srow;
            int scol = kbase + ((schw ^ (row & 3)) * 8);   // pre-swizzled source
            GLOAD16(A  + (size_t)(mBase + row) * DD + scol, &sA[slot][r*4096 + tid*8]);
            GLOAD16(Bm + (size_t)(nBase + row) * DD + scol, &sB[slot][r*4096 + tid*8]);
        }
    };

    stage(0); stage(1); stage(2);   // prologue: 3 k-halves in flight (12 loads)

    for (int n = 0; n < 32; ++n) {
        if (n == 31) { asm volatile("s_waitcnt vmcnt(0)" ::: "memory"); }
        else         { asm volatile("s_waitcnt vmcnt(4)" ::: "memory"); }
        __builtin_amdgcn_s_barrier();        // collective: kh n confirmed, slot (n-1)&3 free
        if (n + 3 < 32) stage(n + 3);        // into slot (n+3)&3 == (n-1)&3
        const int slot = n & 3;
        bf16x8 af[8], bfv[4];
        #pragma unroll
        for (int rf = 0; rf < 8; ++rf) {
            int ra = wm*128 + rf*16 + lr;
            af[rf] = *(const bf16x8*)&sA[slot][ra*32 + ((lg ^ (ra & 3)) * 8)];
        }
        #pragma unroll
        for (int cf = 0; cf < 4; ++cf) {
            int rb = wn*64 + cf*16 + lr;
            bfv[cf] = *(const bf16x8*)&sB[slot][rb*32 + ((lg ^ (rb & 3)) * 8)];
        }
        __builtin_amdgcn_s_setprio(1);
        #pragma unroll
        for (int rf = 0; rf < 8; ++rf)
            #pragma unroll
            for (int cf = 0; cf < 4; ++cf)
                acc[rf][cf] = __builtin_amdgcn_mfma_f32_16x16x32_bf16(
                    af[rf], bfv[cf], acc[rf][cf], 0, 0, 0);
        __builtin_amdgcn_s_setprio(0);
    }

    // ---- epilogue: RoPE for Q/K blocks (bx<8), plain store for V (bx>=8)
    if (bx < 8) {
        const bool isQ = bx < 4;
        unsigned short* dst = isQ ? Qb : Kb;
        const float qsc = isQ ? 0.1803368801111244f : 1.0f;   // 0.125*log2e on Q only
        const int colbase = (bx & 3)*256 + wn*64;             // within [0,1024), 64-aligned
        #pragma unroll
        for (int rr = 0; rr < 8; ++rr) {
            #pragma unroll
            for (int j = 0; j < 4; ++j) {
                int row = mBase + wm*128 + rr*16 + lg*4 + j;
                int pos = pids[row];
                #pragma unroll
                for (int cf = 0; cf < 2; ++cf) {
                    int d = cf*16 + lr;                        // 0..31
                    float cc = tabc[pos*32 + d];
                    float sn = tabs[pos*32 + d];
                    float a  = acc[rr][cf][j];
                    float bb2 = acc[rr][cf+2][j];
                    dst[(size_t)row * DD + colbase + d]      = f2bf((a*cc - bb2*sn) * qsc);
                    dst[(size_t)row * DD + colbase + d + 32] = f2bf((bb2*cc + a*sn) * qsc);
                }
            }
        }
    } else {
        const int colbase = (bx - 8)*256 + wn*64;
        #pragma unroll
        for (int rr = 0; rr < 8; ++rr) {
            #pragma unroll
            for (int j = 0; j < 4; ++j) {
                int row = mBase + wm*128 + rr*16 + lg*4 + j;
                #pragma unroll
                for (int cf = 0; cf < 4; ++cf)
                    Vr[(size_t)row * DD + colbase + cf*16 + lr] = f2bf(acc[rr][cf][j]);
            }
        }
    }
}

// ---------------------------------------------------------------- out-proj GEMM + bias
__global__ __launch_bounds__(256) void gemm_bt(
    const unsigned short* __restrict__ A, const unsigned short* __restrict__ Bm,
    float* __restrict__ Cout, const float* __restrict__ bias,
    int M, int N, int K)
{
    __shared__ __align__(16) unsigned short sA[2][128 * 64];
    __shared__ __align__(16) unsigned short sB[2][128 * 64];
    const int tid = threadIdx.x;
    const int w = tid >> 6, l = tid & 63;
    const int wm = w >> 1, wn = w & 1;
    const int lr = l & 15, lg = l >> 4;
    const int nwg = gridDim.x;
    const int cpx = nwg >> 3;
    const int swz = (blockIdx.x & 7) * cpx + (blockIdx.x >> 3);
    const int nbx = N >> 7;
    const int bx = swz % nbx, by = swz / nbx;
    const int mBase = by * 128, nBase = bx * 128;
    const int srow = tid >> 3;
    const int skof = (tid & 7) * 8;

    f32x4 acc[4][4] = {};

    #pragma unroll
    for (int i = 0; i < 4; ++i) {
        GLOAD16(A  + (size_t)(mBase + i*32 + srow) * K + skof, &sA[0][i*2048 + w*512]);
        GLOAD16(Bm + (size_t)(nBase + i*32 + srow) * K + skof, &sB[0][i*2048 + w*512]);
    }
    int cur = 0;

    for (int kt = 0; kt < K; kt += 64) {
        __syncthreads();
        if (kt + 64 < K) {
            #pragma unroll
            for (int i = 0; i < 4; ++i) {
                GLOAD16(A  + (size_t)(mBase + i*32 + srow) * K + kt + 64 + skof, &sA[cur^1][i*2048 + w*512]);
                GLOAD16(Bm + (size_t)(nBase + i*32 + srow) * K + kt + 64 + skof, &sB[cur^1][i*2048 + w*512]);
            }
        }
        #pragma unroll
        for (int kk = 0; kk < 2; ++kk) {
            bf16x8 af[4], bfv[4];
            #pragma unroll
            for (int mi = 0; mi < 4; ++mi)
                af[mi] = *(const bf16x8*)&sA[cur][(wm*64 + mi*16 + lr)*64 + kk*32 + lg*8];
            #pragma unroll
            for (int ni = 0; ni < 4; ++ni)
                bfv[ni] = *(const bf16x8*)&sB[cur][(wn*64 + ni*16 + lr)*64 + kk*32 + lg*8];
            #pragma unroll
            for (int mi = 0; mi < 4; ++mi)
                #pragma unroll
                for (int ni = 0; ni < 4; ++ni)
                    acc[mi][ni] = __builtin_amdgcn_mfma_f32_16x16x32_bf16(af[mi], bfv[ni], acc[mi][ni], 0, 0, 0);
        }
        cur ^= 1;
    }
    #pragma unroll
    for (int mi = 0; mi < 4; ++mi) {
        #pragma unroll
        for (int j = 0; j < 4; ++j) {
            int row = mBase + wm*64 + mi*16 + lg*4 + j;
            #pragma unroll
            for (int ni = 0; ni < 4; ++ni) {
                int col = nBase + wn*64 + ni*16 + lr;
                Cout[(size_t)row * N + col] = acc[mi][ni][j] + bias[col];
            }
        }
    }
}

// ---------------------------------------------------------------- V transpose via chunk-swizzled LDS tile
__global__ __launch_bounds__(256) void v_transpose(
    const unsigned short* __restrict__ Vr, unsigned short* __restrict__ Vt)
{
    __shared__ __align__(16) unsigned short sT[64 * 64];
    const int bh = blockIdx.y;          // 0..31
    const int st = blockIdx.x;          // 0..31 (s-tile)
    const int b = bh >> 4, h = bh & 15;
    const int tid = threadIdx.x;
    #pragma unroll
    for (int i = 0; i < 2; ++i) {
        int c = tid + i*256;            // chunk 0..511
        int s = c >> 3, cb = c & 7;
        const unsigned short* src = Vr + (size_t)(b*SS + st*64 + s) * DD + h*64 + cb*8;
        uint4 v = *(const uint4*)src;
        *(uint4*)&sT[s*64 + ((cb ^ (s >> 3)) * 8)] = v;   // chunk-swizzled store
    }
    __syncthreads();
    #pragma unroll
    for (int i = 0; i < 2; ++i) {
        int c = tid + i*256;
        int d = c >> 3, sb = c & 7;
        union { unsigned short u[8]; uint4 v; } o;
        #pragma unroll
        for (int e = 0; e < 8; ++e) {
            int s = sb*8 + e;
            o.u[e] = sT[s*64 + (((d >> 3) ^ (s >> 3)) * 8) + (d & 7)];
        }
        *(uint4*)(Vt + (size_t)(bh*64 + d) * SS + st*64 + sb*8) = o.v;
    }
}

// ---------------------------------------------------------------- flash attention fwd (causal), kv-split (R21)
__global__ __launch_bounds__(256, 4) void attn_fwd(
    const unsigned short* __restrict__ Qb,   // [4096][1024], pre-scaled by 0.125*log2e
    const unsigned short* __restrict__ Kb,   // [4096][1024]
    const unsigned short* __restrict__ Vt,   // [2048][2048]
    float* __restrict__ OpA,                 // [4096][1024] f32 partial (half 0)
    float* __restrict__ OpB,                 // [4096][1024] f32 partial (half 1)
    float* __restrict__ Ml)                  // [2][32][2048][2] f32 (m, l)
{
    __shared__ __align__(16) unsigned short sK[2][4096];   // [64 rows][64 d] per buf, 8KB
    __shared__ __align__(16) unsigned short sV[2][4096];   // [64 d][64 s] per buf
    const int tid = threadIdx.x;
    const int w = tid >> 6, l = tid & 63;
    const int lq = l & 31;
    const int hi5 = l >> 5;
    const bool hb = hi5 != 0;

    const int xcd  = blockIdx.x & 7;
    const int c    = blockIdx.x >> 3;        // 0..127
    const int gsel = (c >> 1) & 3;
    const int half = c & 1;
    const int t2   = c >> 3;                 // 0..15
    const int qt   = (t2 < 8) ? t2 : 23 - t2;   // 128-row q-tile index 0..15
    const int bh   = xcd * 4 + gsel;
    const int b = bh >> 4, h = bh & 15;

    const int srow = tid >> 3;               // 0..31
    const int skof = (tid & 7) * 8;
    const int sksw = skof ^ ((srow & 7) * 8);   // pre-swizzled staging col (elements)
    const int sw   = (lq & 7) * 8;              // read-side XOR term
    const float THR = 12.0f;

    // Q fragments: Q[q = qt*128 + w*32 + lq][dk = dkc*16 + hi5*8 + e]
    bf16x8 qf[4];
    {
        const unsigned short* qp = Qb + (size_t)(b*SS + qt*128 + w*32 + lq) * DD + h*64 + hi5*8;
        #pragma unroll
        for (int dkc = 0; dkc < 4; ++dkc)
            qf[dkc] = *(const bf16x8*)(qp + dkc*16);
    }
    const int q_lane = qt*128 + w*32 + lq;
    const int wbase  = qt*128 + w*32;        // wave's min q-row (mask gate)
    const int kt0    = half * (qt + 1);      // first 64-wide kv sub-tile of this half
    const int nsub   = qt + 1;               // sub-steps in this half

    f32x16 o0 = {}, o1 = {};
    float mrow = -3.0e38f, lsum = 0.f;
    int cur = 0;

    // stage 64-wide kv sub-tile kt into buf bb
    auto stage = [&](int kt, int bb) {
        #pragma unroll
        for (int r = 0; r < 2; ++r) {
            GLOAD16(Kb + (size_t)(b*SS + kt*64 + r*32 + srow) * DD + h*64 + sksw,
                    &sK[bb][r*2048 + w*512]);
            GLOAD16(Vt + (size_t)(bh*64 + r*32 + srow) * SS + kt*64 + sksw,
                    &sV[bb][r*2048 + w*512]);
        }
    };

    stage(kt0, 0);

    for (int s = 0; s < nsub; ++s) {
        const int kt = kt0 + s;
        __syncthreads();   // vmcnt drained: buf[cur] staged; all waves done with buf[cur^1]
        if (s + 1 < nsub) stage(kt + 1, cur ^ 1);

        // QK^T swapped: lane holds S[k][q=lq]
        f32x16 p0 = {}, p1 = {};
        __builtin_amdgcn_s_setprio(1);
        #pragma unroll
        for (int dkc = 0; dkc < 4; ++dkc) {
            bf16x8 k0 = *(const bf16x8*)&sK[cur][lq*64 + ((dkc*16 + hi5*8) ^ sw)];
            p0 = __builtin_amdgcn_mfma_f32_32x32x16_bf16(k0, qf[dkc], p0, 0, 0, 0);
        }
        #pragma unroll
        for (int dkc = 0; dkc < 4; ++dkc) {
            bf16x8 k1 = *(const bf16x8*)&sK[cur][2048 + lq*64 + ((dkc*16 + hi5*8) ^ sw)];
            p1 = __builtin_amdgcn_mfma_f32_32x32x16_bf16(k1, qf[dkc], p1, 0, 0, 0);
        }
        __builtin_amdgcn_s_setprio(0);

        if (kt*64 + 63 > wbase) {   // wave-uniform gate; element-exact mask inside
            const int kb0 = kt*64 + 4*hi5;
            #pragma unroll
            for (int r = 0; r < 16; ++r) {
                const int cr = (r & 3) + 8*(r >> 2);
                if (kb0 + cr > q_lane)      p0[r] = -1e30f;
                if (kb0 + 32 + cr > q_lane) p1[r] = -1e30f;
            }
        }

        // row max: in-lane tree + partner swap
        float tt[16];
        #pragma unroll
        for (int r = 0; r < 16; ++r) tt[r] = fmaxf(p0[r], p1[r]);
        #pragma unroll
        for (int s2 = 8; s2 >= 1; s2 >>= 1)
            #pragma unroll
            for (int r = 0; r < 8; ++r)
                if (r < s2) tt[r] = fmaxf(tt[r], tt[r + s2]);
        float tmx = fmaxf(tt[0], swap_half(tt[0], hb));

        // defer-max (T13)
        float growth = tmx - mrow;
        if (!__all(growth <= THR)) {
            float mnew = fmaxf(mrow, tmx);
            float alpha = exp2f(mrow - mnew);
            lsum *= alpha;
            mrow = mnew;
            #pragma unroll
            for (int r = 0; r < 16; ++r) { o0[r] *= alpha; o1[r] *= alpha; }
        }

        // P = exp2(S - m), per-lane partial sum
        #pragma unroll
        for (int r = 0; r < 16; ++r) {
            p0[r] = exp2f(p0[r] - mrow);
            p1[r] = exp2f(p1[r] - mrow);
        }
        float st[16];
        #pragma unroll
        for (int r = 0; r < 16; ++r) st[r] = p0[r] + p1[r];
        #pragma unroll
        for (int s2 = 8; s2 >= 1; s2 >>= 1)
            #pragma unroll
            for (int r = 0; r < 8; ++r)
                if (r < s2) st[r] += st[r + s2];
        lsum += st[0];

        // PV swapped: O^T[d][q] += mfma(V^T-frag, P-frag); in-register P conversion (T12)
        __builtin_amdgcn_s_setprio(1);
        {
            bf16x8 pv, vf;
            pv = cvt_chunk<0>(p0);   // k 0..15
            vf = *(const bf16x8*)&sV[cur][lq*64 + ((0*16 + hi5*8) ^ sw)];
            o0 = __builtin_amdgcn_mfma_f32_32x32x16_bf16(vf, pv, o0, 0, 0, 0);
            vf = *(const bf16x8*)&sV[cur][2048 + lq*64 + ((0*16 + hi5*8) ^ sw)];
            o1 = __builtin_amdgcn_mfma_f32_32x32x16_bf16(vf, pv, o1, 0, 0, 0);
            pv = cvt_chunk<8>(p0);   // k 16..31
            vf = *(const bf16x8*)&sV[cur][lq*64 + ((1*16 + hi5*8) ^ sw)];
            o0 = __builtin_amdgcn_mfma_f32_32x32x16_bf16(vf, pv, o0, 0, 0, 0);
            vf = *(const bf16x8*)&sV[cur][2048 + lq*64 + ((1*16 + hi5*8) ^ sw)];
            o1 = __builtin_amdgcn_mfma_f32_32x32x16_bf16(vf, pv, o1, 0, 0, 0);
            pv = cvt_chunk<0>(p1);   // k 32..47
            vf = *(const bf16x8*)&sV[cur][lq*64 + ((2*16 + hi5*8) ^ sw)];
            o0 = __builtin_amdgcn_mfma_f32_32x32x16_bf16(vf, pv, o0, 0, 0, 0);
            vf = *(const bf16x8*)&sV[cur][2048 + lq*64 + ((2*16 + hi5*8) ^ sw)];
            o1 = __builtin_amdgcn_mfma_f32_32x32x16_bf16(vf, pv, o1, 0, 0, 0);
            pv = cvt_chunk<8>(p1);   // k 48..63
            vf = *(const bf16x8*)&sV[cur][lq*64 + ((3*16 + hi5*8) ^ sw)];
            o0 = __builtin_amdgcn_mfma_f32_32x32x16_bf16(vf, pv, o0, 0, 0, 0);
            vf = *(const bf16x8*)&sV[cur][2048 + lq*64 + ((3*16 + hi5*8) ^ sw)];
            o1 = __builtin_amdgcn_mfma_f32_32x32x16_bf16(vf, pv, o1, 0, 0, 0);
        }
        __builtin_amdgcn_s_setprio(0);
        cur ^= 1;
    }

    // ---- epilogue: partner-sum l, store UNNORMALIZED f32 partial O via per-wave LDS
    __syncthreads();   // all compute done; LDS free for reuse
    float ls = lsum + swap_half(lsum, hb);
    float* sOf = (w < 2) ? (float*)&sK[w][0] : (float*)&sV[w - 2][0];   // [32 q][64 d] f32

    #pragma unroll
    for (int g2 = 0; g2 < 4; ++g2) {
        f32x4 t0, t1;
        #pragma unroll
        for (int j = 0; j < 4; ++j) { t0[j] = o0[g2*4 + j]; t1[j] = o1[g2*4 + j]; }
        *(f32x4*)&sOf[lq*64 + g2*8 + hi5*4]      = t0;
        *(f32x4*)&sOf[lq*64 + 32 + g2*8 + hi5*4] = t1;
    }
    asm volatile("s_waitcnt lgkmcnt(0)" ::: "memory");
    __builtin_amdgcn_sched_barrier(0);

    float* Op = half ? OpB : OpA;
    const int row = l >> 1, cb2 = (l & 1) * 32;
    const float* sOr = sOf + row*64 + cb2;
    float* gp = Op + (size_t)(b*SS + qt*128 + w*32 + row) * DD + h*64 + cb2;
    #pragma unroll
    for (int c2 = 0; c2 < 8; ++c2)
        *(f32x4*)(gp + c2*4) = *(const f32x4*)(sOr + c2*4);

    if (!hb) {
        int qrow = qt*128 + w*32 + lq;
        float* mlp = Ml + (((size_t)half*32 + bh)*2048 + qrow)*2;
        mlp[0] = mrow;
        mlp[1] = ls;
    }
}

// ---------------------------------------------------------------- merge kv-split partials
__global__ __launch_bounds__(256) void attn_merge(
    const float* __restrict__ OpA, const float* __restrict__ OpB,
    const float* __restrict__ Ml, unsigned short* __restrict__ Ob)
{
    int e = blockIdx.x * 256 + threadIdx.x;   // 1,048,576 float4 groups
    int row = e >> 8;                          // 4096 rows (256 float4 per row)
    int col = (e & 255) * 4;
    int b = row >> 11, q = row & 2047;
    int h = col >> 6;
    int bh = b*16 + h;
    const float* mlA = Ml + ((size_t)bh*2048 + q)*2;
    const float* mlB = Ml + (((size_t)32 + bh)*2048 + q)*2;
    float mA = mlA[0], lA = mlA[1];
    float mB = mlB[0], lB = mlB[1];
    float m  = fmaxf(mA, mB);
    float sA = exp2f(mA - m), sB = exp2f(mB - m);
    float linv = 1.f / (lA*sA + lB*sB);
    float fa = sA * linv, fb = sB * linv;
    f32x4 a = *(const f32x4*)(OpA + (size_t)e*4);
    f32x4 bq = *(const f32x4*)(OpB + (size_t)e*4);
    union { unsigned short s[4]; uint2 v; } o;
    #pragma unroll
    for (int j = 0; j < 4; ++j)
        o.s[j] = f2bf(a[j]*fa + bq[j]*fb);
    *(uint2*)(Ob + (size_t)e*4) = o.v;
}

// ---------------------------------------------------------------- launch
extern "C" void kernel_launch(void* const* d_in, const int* in_sizes, int n_in,
                              void* d_out, int out_size, void* d_ws, size_t ws_size,
                              hipStream_t stream)
{
    const float* x  = (const float*)d_in[0];
    // d_in[1] = mask (causal tril; implemented analytically)
    const int* pids = (const int*)d_in[2];
    const float* wq = (const float*)d_in[3];
    const float* wk = (const float*)d_in[4];
    const float* wv = (const float*)d_in[5];
    const float* wo = (const float*)d_in[6];
    const float* bo = (const float*)d_in[7];
    float* out = (float*)d_out;

    char* ws = (char*)d_ws;
    unsigned short* xb   = (unsigned short*)(ws);                        // 8 MB
    unsigned short* wqkv = (unsigned short*)(ws + (size_t)( 8u<<20));    // 6 MB
    unsigned short* wob  = (unsigned short*)(ws + (size_t)(14u<<20));    // 2 MB
    unsigned short* Vr   = (unsigned short*)(ws + (size_t)(16u<<20));    // 8 MB (dead after v_transpose)
    float* Ml            = (float*)(ws + (size_t)(16u<<20));             // 1 MB (reuses Vr region)
    float* OpA           = (float*)(ws + (size_t)(24u<<20));             // 16 MB f32 partials (half 0)
    unsigned short* Qb   = (unsigned short*)(ws + (size_t)(40u<<20));    // 8 MB
    unsigned short* Kb   = (unsigned short*)(ws + (size_t)(48u<<20));    // 8 MB
    unsigned short* Vt   = (unsigned short*)(ws + (size_t)(56u<<20));    // 8 MB
    float* tabc          = (float*)(ws + (size_t)(64u<<20));             // 256 KB
    float* tabs          = (float*)(ws + (size_t)(64u<<20) + (256u<<10));// 256 KB
    float* OpB           = out;   // d_out (16 MB f32) free until gemm_bt writes it
    unsigned short* Ob   = xb;    // alias: x_bf16 dead after QKV GEMM

    cast_all<<<dim3(4096), dim3(256), 0, stream>>>(x, wq, wk, wv, wo, xb, wqkv, wob);
    rope_table<<<dim3(256), dim3(256), 0, stream>>>(tabc, tabs);
    gemm_qkv<<<dim3(192), dim3(512), 0, stream>>>(
        xb, wqkv, pids, tabc, tabs, Qb, Kb, Vr);
    v_transpose<<<dim3(32, 32), dim3(256), 0, stream>>>(Vr, Vt);
    attn_fwd<<<dim3(1024), dim3(256), 0, stream>>>(Qb, Kb, Vt, OpA, OpB, Ml);
    attn_merge<<<dim3(4096), dim3(256), 0, stream>>>(OpA, OpB, Ml, Ob);
    gemm_bt<<<dim3(256), dim3(256), 0, stream>>>(
        Ob, wob, out, bo, MROWS, DD, DD);
}

// Round 23
// 137.613 us; speedup vs baseline: 1.0304x; 1.0304x over previous
//
#include <hip/hip_runtime.h>
#include <hip/hip_bf16.h>
#include <cstdint>

#define BB 2
#define SS 2048
#define DD 1024
#define HH 16
#define DK 64
#define MROWS (BB*SS)        // 4096
#define NQKV  (3*DD)         // 3072

typedef __bf16 bf16x8 __attribute__((ext_vector_type(8)));
typedef float  f32x4  __attribute__((ext_vector_type(4)));
typedef float  f32x16 __attribute__((ext_vector_type(16)));
typedef unsigned u32x2 __attribute__((ext_vector_type(2)));

static __device__ __forceinline__ unsigned short f2bf(float f) {
    __bf16 h = (__bf16)f;
    return __builtin_bit_cast(unsigned short, h);
}
static __device__ __forceinline__ float bf2f(unsigned short u) {
    return (float)__builtin_bit_cast(__bf16, u);
}

#define GLOAD16(gsrc, ldst) \
    __builtin_amdgcn_global_load_lds((const __attribute__((address_space(1))) void*)(gsrc), \
                                     (__attribute__((address_space(3))) void*)(ldst), 16, 0, 0)

// v_permlane32_swap_b32: first operand's HIGH half swaps with second operand's LOW half.
static __device__ __forceinline__ void pl32_swap(unsigned &x, unsigned &y) {
#if __has_builtin(__builtin_amdgcn_permlane32_swap)
    u32x2 r = __builtin_amdgcn_permlane32_swap(x, y, false, false);
    x = r[0]; y = r[1];
#else
    asm volatile("v_permlane32_swap_b32 %0, %1" : "+v"(x), "+v"(y));
#endif
}
static __device__ __forceinline__ float swap_half(float v, bool hi) {
    unsigned x = __builtin_bit_cast(unsigned, v), y = x;
    pl32_swap(x, y);
    return __builtin_bit_cast(float, hi ? x : y);
}
// T12: build PV B-frag from 8 f32 C-layout regs (verified R10).
template<int BASE> static __device__ __forceinline__ bf16x8 cvt_chunk(const f32x16 &p) {
    unsigned x0, y0, x1, y1;
    asm("v_cvt_pk_bf16_f32 %0, %1, %2" : "=v"(x0) : "v"(p[BASE+0]), "v"(p[BASE+1]));
    asm("v_cvt_pk_bf16_f32 %0, %1, %2" : "=v"(y0) : "v"(p[BASE+4]), "v"(p[BASE+5]));
    asm("v_cvt_pk_bf16_f32 %0, %1, %2" : "=v"(x1) : "v"(p[BASE+2]), "v"(p[BASE+3]));
    asm("v_cvt_pk_bf16_f32 %0, %1, %2" : "=v"(y1) : "v"(p[BASE+6]), "v"(p[BASE+7]));
    pl32_swap(x0, y0);
    pl32_swap(x1, y1);
    union { unsigned u[4]; bf16x8 v; } r;
    r.u[0] = x0; r.u[1] = x1; r.u[2] = y0; r.u[3] = y1;
    return r.v;
}

// ---------------------------------------------------------------- cast x + weights to bf16
__global__ void cast_all(const float* __restrict__ x,  const float* __restrict__ wq,
                         const float* __restrict__ wk, const float* __restrict__ wv,
                         const float* __restrict__ wo,
                         unsigned short* __restrict__ xb, unsigned short* __restrict__ wqkv,
                         unsigned short* __restrict__ wob)
{
    const int NX = MROWS * DD;      // 4194304
    const int NW = DD * DD;         // 1048576
    const int total = (NX + 4 * NW) / 8;
    for (int i = blockIdx.x * blockDim.x + threadIdx.x; i < total; i += gridDim.x * blockDim.x) {
        int base = i * 8;
        const float* src; unsigned short* dst; int off;
        if      (base < NX)          { src = x;  dst = xb;          off = base; }
        else if (base < NX + NW)     { src = wq; dst = wqkv;        off = base - NX; }
        else if (base < NX + 2*NW)   { src = wk; dst = wqkv + NW;   off = base - NX - NW; }
        else if (base < NX + 3*NW)   { src = wv; dst = wqkv + 2*NW; off = base - NX - 2*NW; }
        else                         { src = wo; dst = wob;         off = base - NX - 3*NW; }
        float4 a = *(const float4*)(src + off);
        float4 b = *(const float4*)(src + off + 4);
        union { unsigned short s[8]; uint4 v; } u;
        u.s[0] = f2bf(a.x); u.s[1] = f2bf(a.y); u.s[2] = f2bf(a.z); u.s[3] = f2bf(a.w);
        u.s[4] = f2bf(b.x); u.s[5] = f2bf(b.y); u.s[6] = f2bf(b.z); u.s[7] = f2bf(b.w);
        *(uint4*)(dst + off) = u.v;
    }
}

// ---------------------------------------------------------------- RoPE cos/sin table [2048][32]
__global__ void rope_table(float* __restrict__ tabc, float* __restrict__ tabs)
{
    int i = blockIdx.x * blockDim.x + threadIdx.x;   // 65536 threads
    int s = i >> 5, d = i & 31;
    float inv = exp2f(-(float)d * (13.287712379549449f / 32.f));  // 10000^(-d/32)
    float ang = (float)s * inv;
    tabc[i] = cosf(ang);
    tabs[i] = sinf(ang);
}

// ---------------------------------------------------------------- fused QKV GEMM + RoPE epilogue
// 256x256, 8 waves, T4 counted-vmcnt pipeline (R22 with 2 fixes):
//  (1) vmcnt(8) not vmcnt(4): outstanding = 12 loads (3 k-halves); wait <=8 confirms
//      exactly the oldest 4 (kh n) -- R22 over-waited one extra kh.
//  (2) swizzle on (row>>1)&3 not row&3: [256][32] rows are 64B (16 banks), same-parity
//      rows share a bank-half; (row>>1) cycles all 4 chunks across same-parity lanes
//      -> 2-way (free) instead of 4-way (2.36M conflicts in R22).
__global__ __launch_bounds__(512) void gemm_qkv(
    const unsigned short* __restrict__ A, const unsigned short* __restrict__ Bm,
    const int* __restrict__ pids,
    const float* __restrict__ tabc, const float* __restrict__ tabs,
    unsigned short* __restrict__ Qb, unsigned short* __restrict__ Kb,
    unsigned short* __restrict__ Vr)
{
    __shared__ __align__(16) unsigned short sA[4][8192];   // 4 k-half slots [256][32]
    __shared__ __align__(16) unsigned short sB[4][8192];
    const int tid = threadIdx.x;
    const int w = tid >> 6, l = tid & 63;
    const int wm = w >> 2, wn = w & 3;       // 2M x 4N wave grid
    const int lr = l & 15, lg = l >> 4;
    // XCD swizzle: 192 blocks = 8 XCDs x 24 (bijective)
    const int swz = (blockIdx.x & 7) * 24 + (blockIdx.x >> 3);
    const int bx = swz % 12, by = swz / 12;
    const int mBase = by * 256;
    const int nBase = bx * 256;
    const int srow = tid >> 2;               // 0..127 staging row within round
    const int schw = tid & 3;                // staging chunk-word

    f32x4 acc[8][4] = {};

    // stage k-half kh (0..31) into slot kh&3; 4 loads/thread (2 rounds x A,B)
    auto stage = [&](int kh) {
        const int slot = kh & 3;
        const int kbase = kh * 32;
        #pragma unroll
        for (int r = 0; r < 2; ++r) {
            int row = r * 128 + srow;
            int scol = kbase + ((schw ^ ((row >> 1) & 3)) * 8);   // pre-swizzled source
            GLOAD16(A  + (size_t)(mBase + row) * DD + scol, &sA[slot][r*4096 + tid*8]);
            GLOAD16(Bm + (size_t)(nBase + row) * DD + scol, &sB[slot][r*4096 + tid*8]);
        }
    };

    stage(0); stage(1); stage(2);   // prologue: 3 k-halves in flight (12 loads)

    for (int n = 0; n < 32; ++n) {
        if (n == 31) { asm volatile("s_waitcnt vmcnt(0)" ::: "memory"); }
        else         { asm volatile("s_waitcnt vmcnt(8)" ::: "memory"); }
        __builtin_amdgcn_s_barrier();        // collective: kh n confirmed, slot (n-1)&3 free
        if (n + 3 < 32) stage(n + 3);        // into slot (n+3)&3 == (n-1)&3
        const int slot = n & 3;
        bf16x8 af[8], bfv[4];
        #pragma unroll
        for (int rf = 0; rf < 8; ++rf) {
            int ra = wm*128 + rf*16 + lr;
            af[rf] = *(const bf16x8*)&sA[slot][ra*32 + ((lg ^ ((ra >> 1) & 3)) * 8)];
        }
        #pragma unroll
        for (int cf = 0; cf < 4; ++cf) {
            int rb = wn*64 + cf*16 + lr;
            bfv[cf] = *(const bf16x8*)&sB[slot][rb*32 + ((lg ^ ((rb >> 1) & 3)) * 8)];
        }
        __builtin_amdgcn_s_setprio(1);
        #pragma unroll
        for (int rf = 0; rf < 8; ++rf)
            #pragma unroll
            for (int cf = 0; cf < 4; ++cf)
                acc[rf][cf] = __builtin_amdgcn_mfma_f32_16x16x32_bf16(
                    af[rf], bfv[cf], acc[rf][cf], 0, 0, 0);
        __builtin_amdgcn_s_setprio(0);
    }

    // ---- epilogue: RoPE for Q/K blocks (bx<8), plain store for V (bx>=8)
    if (bx < 8) {
        const bool isQ = bx < 4;
        unsigned short* dst = isQ ? Qb : Kb;
        const float qsc = isQ ? 0.1803368801111244f : 1.0f;   // 0.125*log2e on Q only
        const int colbase = (bx & 3)*256 + wn*64;             // within [0,1024), 64-aligned
        #pragma unroll
        for (int rr = 0; rr < 8; ++rr) {
            #pragma unroll
            for (int j = 0; j < 4; ++j) {
                int row = mBase + wm*128 + rr*16 + lg*4 + j;
                int pos = pids[row];
                #pragma unroll
                for (int cf = 0; cf < 2; ++cf) {
                    int d = cf*16 + lr;                        // 0..31
                    float cc = tabc[pos*32 + d];
                    float sn = tabs[pos*32 + d];
                    float a  = acc[rr][cf][j];
                    float bb2 = acc[rr][cf+2][j];
                    dst[(size_t)row * DD + colbase + d]      = f2bf((a*cc - bb2*sn) * qsc);
                    dst[(size_t)row * DD + colbase + d + 32] = f2bf((bb2*cc + a*sn) * qsc);
                }
            }
        }
    } else {
        const int colbase = (bx - 8)*256 + wn*64;
        #pragma unroll
        for (int rr = 0; rr < 8; ++rr) {
            #pragma unroll
            for (int j = 0; j < 4; ++j) {
                int row = mBase + wm*128 + rr*16 + lg*4 + j;
                #pragma unroll
                for (int cf = 0; cf < 4; ++cf)
                    Vr[(size_t)row * DD + colbase + cf*16 + lr] = f2bf(acc[rr][cf][j]);
            }
        }
    }
}

// ---------------------------------------------------------------- out-proj GEMM + bias
// T3-min dbuf (R12/R14 structure): 256 blocks = 1 block/CU.
__global__ __launch_bounds__(256) void gemm_bt(
    const unsigned short* __restrict__ A, const unsigned short* __restrict__ Bm,
    float* __restrict__ Cout, const float* __restrict__ bias,
    int M, int N, int K)
{
    __shared__ __align__(16) unsigned short sA[2][128 * 64];
    __shared__ __align__(16) unsigned short sB[2][128 * 64];
    const int tid = threadIdx.x;
    const int w = tid >> 6, l = tid & 63;
    const int wm = w >> 1, wn = w & 1;
    const int lr = l & 15, lg = l >> 4;
    const int nwg = gridDim.x;
    const int cpx = nwg >> 3;
    const int swz = (blockIdx.x & 7) * cpx + (blockIdx.x >> 3);
    const int nbx = N >> 7;
    const int bx = swz % nbx, by = swz / nbx;
    const int mBase = by * 128, nBase = bx * 128;
    const int srow = tid >> 3;
    const int skof = (tid & 7) * 8;

    f32x4 acc[4][4] = {};

    #pragma unroll
    for (int i = 0; i < 4; ++i) {
        GLOAD16(A  + (size_t)(mBase + i*32 + srow) * K + skof, &sA[0][i*2048 + w*512]);
        GLOAD16(Bm + (size_t)(nBase + i*32 + srow) * K + skof, &sB[0][i*2048 + w*512]);
    }
    int cur = 0;

    for (int kt = 0; kt < K; kt += 64) {
        __syncthreads();
        if (kt + 64 < K) {
            #pragma unroll
            for (int i = 0; i < 4; ++i) {
                GLOAD16(A  + (size_t)(mBase + i*32 + srow) * K + kt + 64 + skof, &sA[cur^1][i*2048 + w*512]);
                GLOAD16(Bm + (size_t)(nBase + i*32 + srow) * K + kt + 64 + skof, &sB[cur^1][i*2048 + w*512]);
            }
        }
        #pragma unroll
        for (int kk = 0; kk < 2; ++kk) {
            bf16x8 af[4], bfv[4];
            #pragma unroll
            for (int mi = 0; mi < 4; ++mi)
                af[mi] = *(const bf16x8*)&sA[cur][(wm*64 + mi*16 + lr)*64 + kk*32 + lg*8];
            #pragma unroll
            for (int ni = 0; ni < 4; ++ni)
                bfv[ni] = *(const bf16x8*)&sB[cur][(wn*64 + ni*16 + lr)*64 + kk*32 + lg*8];
            #pragma unroll
            for (int mi = 0; mi < 4; ++mi)
                #pragma unroll
                for (int ni = 0; ni < 4; ++ni)
                    acc[mi][ni] = __builtin_amdgcn_mfma_f32_16x16x32_bf16(af[mi], bfv[ni], acc[mi][ni], 0, 0, 0);
        }
        cur ^= 1;
    }
    #pragma unroll
    for (int mi = 0; mi < 4; ++mi) {
        #pragma unroll
        for (int j = 0; j < 4; ++j) {
            int row = mBase + wm*64 + mi*16 + lg*4 + j;
            #pragma unroll
            for (int ni = 0; ni < 4; ++ni) {
                int col = nBase + wn*64 + ni*16 + lr;
                Cout[(size_t)row * N + col] = acc[mi][ni][j] + bias[col];
            }
        }
    }
}

// ---------------------------------------------------------------- V transpose via chunk-swizzled LDS tile
// Vr [4096][1024] -> Vt [32*64][2048]
__global__ __launch_bounds__(256) void v_transpose(
    const unsigned short* __restrict__ Vr, unsigned short* __restrict__ Vt)
{
    __shared__ __align__(16) unsigned short sT[64 * 64];
    const int bh = blockIdx.y;          // 0..31
    const int st = blockIdx.x;          // 0..31 (s-tile)
    const int b = bh >> 4, h = bh & 15;
    const int tid = threadIdx.x;
    #pragma unroll
    for (int i = 0; i < 2; ++i) {
        int c = tid + i*256;            // chunk 0..511
        int s = c >> 3, cb = c & 7;
        const unsigned short* src = Vr + (size_t)(b*SS + st*64 + s) * DD + h*64 + cb*8;
        uint4 v = *(const uint4*)src;
        *(uint4*)&sT[s*64 + ((cb ^ (s >> 3)) * 8)] = v;   // chunk-swizzled store
    }
    __syncthreads();
    #pragma unroll
    for (int i = 0; i < 2; ++i) {
        int c = tid + i*256;
        int d = c >> 3, sb = c & 7;
        union { unsigned short u[8]; uint4 v; } o;
        #pragma unroll
        for (int e = 0; e < 8; ++e) {
            int s = sb*8 + e;
            o.u[e] = sT[s*64 + (((d >> 3) ^ (s >> 3)) * 8) + (d & 7)];
        }
        *(uint4*)(Vt + (size_t)(bh*64 + d) * SS + st*64 + sb*8) = o.v;
    }
}

// ---------------------------------------------------------------- flash attention fwd (causal)
// R20 structure: T12, 4 waves x 32 q-rows = 128-row q-tile, KVBLK=128 LDS staging,
// QK for both sub-steps up front (T15-style ordering).
__global__ __launch_bounds__(256, 2) void attn_fwd(
    const unsigned short* __restrict__ Qb,   // [4096][1024], pre-scaled by 0.125*log2e
    const unsigned short* __restrict__ Kb,   // [4096][1024]
    const unsigned short* __restrict__ Vt,   // [2048][2048]
    unsigned short* __restrict__ Ob)         // [4096][1024]
{
    __shared__ __align__(16) unsigned short sK[2][8192];   // [128 k-rows][64 d], 16KB/buf
    __shared__ __align__(16) unsigned short sV[2][8192];   // 2 panels of [64 d][64 s]
    const int tid = threadIdx.x;
    const int w = tid >> 6, l = tid & 63;
    const int lq = l & 31;
    const int hi5 = l >> 5;
    const bool hb = hi5 != 0;

    const int xcd  = blockIdx.x & 7;
    const int c    = blockIdx.x >> 3;        // 0..63
    const int gsel = c & 3;
    const int t    = c >> 2;                 // 0..15
    const int qt   = (t < 8) ? t : 23 - t;   // 128-row q-tile index 0..15
    const int bh   = xcd * 4 + gsel;
    const int b = bh >> 4, h = bh & 15;

    const int srow = tid >> 3;               // 0..31
    const int skof = (tid & 7) * 8;
    const int sksw = skof ^ ((srow & 7) * 8);   // pre-swizzled staging col (elements)
    const int sw   = (lq & 7) * 8;              // read-side XOR term
    const float THR = 12.0f;

    // Q fragments: Q[q = qt*128 + w*32 + lq][dk = dkc*16 + hi5*8 + e]
    bf16x8 qf[4];
    {
        const unsigned short* qp = Qb + (size_t)(b*SS + qt*128 + w*32 + lq) * DD + h*64 + hi5*8;
        #pragma unroll
        for (int dkc = 0; dkc < 4; ++dkc)
            qf[dkc] = *(const bf16x8*)(qp + dkc*16);
    }
    const int q_lane = qt*128 + w*32 + lq;
    const int wbase  = qt*128 + w*32;        // wave's min q-row (mask gate)

    f32x16 o0 = {}, o1 = {};
    float mrow = -3.0e38f, lsum = 0.f;
    int cur = 0;

    // stage 128-wide kv-tile ktt into buf bb
    auto stage = [&](int ktt, int bb) {
        #pragma unroll
        for (int r = 0; r < 4; ++r)
            GLOAD16(Kb + (size_t)(b*SS + ktt*128 + r*32 + srow) * DD + h*64 + sksw,
                    &sK[bb][r*2048 + w*512]);
        #pragma unroll
        for (int s = 0; s < 2; ++s)
            #pragma unroll
            for (int r = 0; r < 2; ++r)
                GLOAD16(Vt + (size_t)(bh*64 + r*32 + srow) * SS + ktt*128 + s*64 + sksw,
                        &sV[bb][s*4096 + r*2048 + w*512]);
    };

    stage(0, 0);

    for (int ktt = 0; ktt <= qt; ++ktt) {
        __syncthreads();   // vmcnt drained: buf[cur] staged; all waves done with buf[cur^1]
        if (ktt < qt) stage(ktt + 1, cur ^ 1);

        // ---- QK^T for BOTH sub-steps up front (independent MFMA batches)
        f32x16 pa0 = {}, pa1 = {};   // sub-step 0
        f32x16 pb0 = {}, pb1 = {};   // sub-step 1
        __builtin_amdgcn_s_setprio(1);
        #pragma unroll
        for (int dkc = 0; dkc < 4; ++dkc) {
            bf16x8 k0 = *(const bf16x8*)&sK[cur][lq*64 + ((dkc*16 + hi5*8) ^ sw)];
            pa0 = __builtin_amdgcn_mfma_f32_32x32x16_bf16(k0, qf[dkc], pa0, 0, 0, 0);
        }
        #pragma unroll
        for (int dkc = 0; dkc < 4; ++dkc) {
            bf16x8 k1 = *(const bf16x8*)&sK[cur][2048 + lq*64 + ((dkc*16 + hi5*8) ^ sw)];
            pa1 = __builtin_amdgcn_mfma_f32_32x32x16_bf16(k1, qf[dkc], pa1, 0, 0, 0);
        }
        #pragma unroll
        for (int dkc = 0; dkc < 4; ++dkc) {
            bf16x8 k2 = *(const bf16x8*)&sK[cur][4096 + lq*64 + ((dkc*16 + hi5*8) ^ sw)];
            pb0 = __builtin_amdgcn_mfma_f32_32x32x16_bf16(k2, qf[dkc], pb0, 0, 0, 0);
        }
        #pragma unroll
        for (int dkc = 0; dkc < 4; ++dkc) {
            bf16x8 k3 = *(const bf16x8*)&sK[cur][4096 + 2048 + lq*64 + ((dkc*16 + hi5*8) ^ sw)];
            pb1 = __builtin_amdgcn_mfma_f32_32x32x16_bf16(k3, qf[dkc], pb1, 0, 0, 0);
        }
        __builtin_amdgcn_s_setprio(0);

        // ---- SM0 — sub-step kt = 2ktt
        {
            const int kt = 2*ktt;
            if (kt*64 + 63 > wbase) {
                const int kb0 = kt*64 + 4*hi5;
                #pragma unroll
                for (int r = 0; r < 16; ++r) {
                    const int cr = (r & 3) + 8*(r >> 2);
                    if (kb0 + cr > q_lane)      pa0[r] = -1e30f;
                    if (kb0 + 32 + cr > q_lane) pa1[r] = -1e30f;
                }
            }
            float tt[16];
            #pragma unroll
            for (int r = 0; r < 16; ++r) tt[r] = fmaxf(pa0[r], pa1[r]);
            #pragma unroll
            for (int s2 = 8; s2 >= 1; s2 >>= 1)
                #pragma unroll
                for (int r = 0; r < 8; ++r)
                    if (r < s2) tt[r] = fmaxf(tt[r], tt[r + s2]);
            float tmx = fmaxf(tt[0], swap_half(tt[0], hb));
            float growth = tmx - mrow;
            if (!__all(growth <= THR)) {
                float mnew = fmaxf(mrow, tmx);
                float alpha = exp2f(mrow - mnew);
                lsum *= alpha;
                mrow = mnew;
                #pragma unroll
                for (int r = 0; r < 16; ++r) { o0[r] *= alpha; o1[r] *= alpha; }
            }
            #pragma unroll
            for (int r = 0; r < 16; ++r) {
                pa0[r] = exp2f(pa0[r] - mrow);
                pa1[r] = exp2f(pa1[r] - mrow);
            }
            float st[16];
            #pragma unroll
            for (int r = 0; r < 16; ++r) st[r] = pa0[r] + pa1[r];
            #pragma unroll
            for (int s2 = 8; s2 >= 1; s2 >>= 1)
                #pragma unroll
                for (int r = 0; r < 8; ++r)
                    if (r < s2) st[r] += st[r + s2];
            lsum += st[0];
        }

        // ---- PV0
        __builtin_amdgcn_s_setprio(1);
        {
            bf16x8 pv, vf;
            pv = cvt_chunk<0>(pa0);
            vf = *(const bf16x8*)&sV[cur][lq*64 + ((0*16 + hi5*8) ^ sw)];
            o0 = __builtin_amdgcn_mfma_f32_32x32x16_bf16(vf, pv, o0, 0, 0, 0);
            vf = *(const bf16x8*)&sV[cur][2048 + lq*64 + ((0*16 + hi5*8) ^ sw)];
            o1 = __builtin_amdgcn_mfma_f32_32x32x16_bf16(vf, pv, o1, 0, 0, 0);
            pv = cvt_chunk<8>(pa0);
            vf = *(const bf16x8*)&sV[cur][lq*64 + ((1*16 + hi5*8) ^ sw)];
            o0 = __builtin_amdgcn_mfma_f32_32x32x16_bf16(vf, pv, o0, 0, 0, 0);
            vf = *(const bf16x8*)&sV[cur][2048 + lq*64 + ((1*16 + hi5*8) ^ sw)];
            o1 = __builtin_amdgcn_mfma_f32_32x32x16_bf16(vf, pv, o1, 0, 0, 0);
            pv = cvt_chunk<0>(pa1);
            vf = *(const bf16x8*)&sV[cur][lq*64 + ((2*16 + hi5*8) ^ sw)];
            o0 = __builtin_amdgcn_mfma_f32_32x32x16_bf16(vf, pv, o0, 0, 0, 0);
            vf = *(const bf16x8*)&sV[cur][2048 + lq*64 + ((2*16 + hi5*8) ^ sw)];
            o1 = __builtin_amdgcn_mfma_f32_32x32x16_bf16(vf, pv, o1, 0, 0, 0);
            pv = cvt_chunk<8>(pa1);
            vf = *(const bf16x8*)&sV[cur][lq*64 + ((3*16 + hi5*8) ^ sw)];
            o0 = __builtin_amdgcn_mfma_f32_32x32x16_bf16(vf, pv, o0, 0, 0, 0);
            vf = *(const bf16x8*)&sV[cur][2048 + lq*64 + ((3*16 + hi5*8) ^ sw)];
            o1 = __builtin_amdgcn_mfma_f32_32x32x16_bf16(vf, pv, o1, 0, 0, 0);
        }
        __builtin_amdgcn_s_setprio(0);

        // ---- SM1 — sub-step kt = 2ktt+1
        {
            const int kt = 2*ktt + 1;
            if (kt*64 + 63 > wbase) {
                const int kb0 = kt*64 + 4*hi5;
                #pragma unroll
                for (int r = 0; r < 16; ++r) {
                    const int cr = (r & 3) + 8*(r >> 2);
                    if (kb0 + cr > q_lane)      pb0[r] = -1e30f;
                    if (kb0 + 32 + cr > q_lane) pb1[r] = -1e30f;
                }
            }
            float tt[16];
            #pragma unroll
            for (int r = 0; r < 16; ++r) tt[r] = fmaxf(pb0[r], pb1[r]);
            #pragma unroll
            for (int s2 = 8; s2 >= 1; s2 >>= 1)
                #pragma unroll
                for (int r = 0; r < 8; ++r)
                    if (r < s2) tt[r] = fmaxf(tt[r], tt[r + s2]);
            float tmx = fmaxf(tt[0], swap_half(tt[0], hb));
            float growth = tmx - mrow;
            if (!__all(growth <= THR)) {
                float mnew = fmaxf(mrow, tmx);
                float alpha = exp2f(mrow - mnew);
                lsum *= alpha;
                mrow = mnew;
                #pragma unroll
                for (int r = 0; r < 16; ++r) { o0[r] *= alpha; o1[r] *= alpha; }
            }
            #pragma unroll
            for (int r = 0; r < 16; ++r) {
                pb0[r] = exp2f(pb0[r] - mrow);
                pb1[r] = exp2f(pb1[r] - mrow);
            }
            float st[16];
            #pragma unroll
            for (int r = 0; r < 16; ++r) st[r] = pb0[r] + pb1[r];
            #pragma unroll
            for (int s2 = 8; s2 >= 1; s2 >>= 1)
                #pragma unroll
                for (int r = 0; r < 8; ++r)
                    if (r < s2) st[r] += st[r + s2];
            lsum += st[0];
        }

        // ---- PV1
        __builtin_amdgcn_s_setprio(1);
        {
            bf16x8 pv, vf;
            pv = cvt_chunk<0>(pb0);
            vf = *(const bf16x8*)&sV[cur][4096 + lq*64 + ((0*16 + hi5*8) ^ sw)];
            o0 = __builtin_amdgcn_mfma_f32_32x32x16_bf16(vf, pv, o0, 0, 0, 0);
            vf = *(const bf16x8*)&sV[cur][4096 + 2048 + lq*64 + ((0*16 + hi5*8) ^ sw)];
            o1 = __builtin_amdgcn_mfma_f32_32x32x16_bf16(vf, pv, o1, 0, 0, 0);
            pv = cvt_chunk<8>(pb0);
            vf = *(const bf16x8*)&sV[cur][4096 + lq*64 + ((1*16 + hi5*8) ^ sw)];
            o0 = __builtin_amdgcn_mfma_f32_32x32x16_bf16(vf, pv, o0, 0, 0, 0);
            vf = *(const bf16x8*)&sV[cur][4096 + 2048 + lq*64 + ((1*16 + hi5*8) ^ sw)];
            o1 = __builtin_amdgcn_mfma_f32_32x32x16_bf16(vf, pv, o1, 0, 0, 0);
            pv = cvt_chunk<0>(pb1);
            vf = *(const bf16x8*)&sV[cur][4096 + lq*64 + ((2*16 + hi5*8) ^ sw)];
            o0 = __builtin_amdgcn_mfma_f32_32x32x16_bf16(vf, pv, o0, 0, 0, 0);
            vf = *(const bf16x8*)&sV[cur][4096 + 2048 + lq*64 + ((2*16 + hi5*8) ^ sw)];
            o1 = __builtin_amdgcn_mfma_f32_32x32x16_bf16(vf, pv, o1, 0, 0, 0);
            pv = cvt_chunk<8>(pb1);
            vf = *(const bf16x8*)&sV[cur][4096 + lq*64 + ((3*16 + hi5*8) ^ sw)];
            o0 = __builtin_amdgcn_mfma_f32_32x32x16_bf16(vf, pv, o0, 0, 0, 0);
            vf = *(const bf16x8*)&sV[cur][4096 + 2048 + lq*64 + ((3*16 + hi5*8) ^ sw)];
            o1 = __builtin_amdgcn_mfma_f32_32x32x16_bf16(vf, pv, o1, 0, 0, 0);
        }
        __builtin_amdgcn_s_setprio(0);
        cur ^= 1;
    }

    // ---- epilogue: normalize, LDS-transpose O (reuse sK, barrier first), coalesced store
    __syncthreads();
    float ls = lsum + swap_half(lsum, hb);
    float inv = 1.f / ls;
    unsigned short* sOw = &sK[0][0] + w * 2048;   // per-wave [32 q][64 d] bf16

    #pragma unroll
    for (int g2 = 0; g2 < 4; ++g2) {
        unsigned ua, ub; uint2 t2;
        float v0 = o0[g2*4+0]*inv, v1 = o0[g2*4+1]*inv, v2 = o0[g2*4+2]*inv, v3 = o0[g2*4+3]*inv;
        asm("v_cvt_pk_bf16_f32 %0, %1, %2" : "=v"(ua) : "v"(v0), "v"(v1));
        asm("v_cvt_pk_bf16_f32 %0, %1, %2" : "=v"(ub) : "v"(v2), "v"(v3));
        t2.x = ua; t2.y = ub;
        *(uint2*)&sOw[lq*64 + g2*8 + hi5*4] = t2;
        float w0 = o1[g2*4+0]*inv, w1 = o1[g2*4+1]*inv, w2 = o1[g2*4+2]*inv, w3 = o1[g2*4+3]*inv;
        asm("v_cvt_pk_bf16_f32 %0, %1, %2" : "=v"(ua) : "v"(w0), "v"(w1));
        asm("v_cvt_pk_bf16_f32 %0, %1, %2" : "=v"(ub) : "v"(w2), "v"(w3));
        t2.x = ua; t2.y = ub;
        *(uint2*)&sOw[lq*64 + 32 + g2*8 + hi5*4] = t2;
    }
    asm volatile("s_waitcnt lgkmcnt(0)" ::: "memory");
    __builtin_amdgcn_sched_barrier(0);

    const int row = l >> 1, cb2 = (l & 1) * 32;
    const unsigned short* sOr = sOw + row*64 + cb2;
    unsigned short* gp = Ob + (size_t)(b*SS + qt*128 + w*32 + row) * DD + h*64 + cb2;
    #pragma unroll
    for (int c2 = 0; c2 < 4; ++c2)
        *(uint4*)(gp + c2*8) = *(const uint4*)(sOr + c2*8);
}

// ---------------------------------------------------------------- launch
extern "C" void kernel_launch(void* const* d_in, const int* in_sizes, int n_in,
                              void* d_out, int out_size, void* d_ws, size_t ws_size,
                              hipStream_t stream)
{
    const float* x  = (const float*)d_in[0];
    // d_in[1] = mask (causal tril; implemented analytically)
    const int* pids = (const int*)d_in[2];
    const float* wq = (const float*)d_in[3];
    const float* wk = (const float*)d_in[4];
    const float* wv = (const float*)d_in[5];
    const float* wo = (const float*)d_in[6];
    const float* bo = (const float*)d_in[7];
    float* out = (float*)d_out;

    char* ws = (char*)d_ws;
    unsigned short* xb   = (unsigned short*)(ws);                        // 8 MB
    unsigned short* wqkv = (unsigned short*)(ws + (size_t)( 8u<<20));    // 6 MB
    unsigned short* wob  = (unsigned short*)(ws + (size_t)(14u<<20));    // 2 MB
    unsigned short* Vr   = (unsigned short*)(ws + (size_t)(16u<<20));    // 8 MB
    unsigned short* Qb   = (unsigned short*)(ws + (size_t)(40u<<20));    // 8 MB
    unsigned short* Kb   = (unsigned short*)(ws + (size_t)(48u<<20));    // 8 MB
    unsigned short* Vt   = (unsigned short*)(ws + (size_t)(56u<<20));    // 8 MB
    float* tabc          = (float*)(ws + (size_t)(64u<<20));             // 256 KB
    float* tabs          = (float*)(ws + (size_t)(64u<<20) + (256u<<10));// 256 KB
    unsigned short* Ob   = xb;  // alias: x_bf16 dead after QKV GEMM

    cast_all<<<dim3(4096), dim3(256), 0, stream>>>(x, wq, wk, wv, wo, xb, wqkv, wob);
    rope_table<<<dim3(256), dim3(256), 0, stream>>>(tabc, tabs);
    gemm_qkv<<<dim3(192), dim3(512), 0, stream>>>(
        xb, wqkv, pids, tabc, tabs, Qb, Kb, Vr);
    v_transpose<<<dim3(32, 32), dim3(256), 0, stream>>>(Vr, Vt);
    attn_fwd<<<dim3(512), dim3(256), 0, stream>>>(Qb, Kb, Vt, Ob);
    gemm_bt<<<dim3(256), dim3(256), 0, stream>>>(
        Ob, wob, out, bo, MROWS, DD, DD);
}

// Round 24
// 131.675 us; speedup vs baseline: 1.0768x; 1.0451x over previous
//
#include <hip/hip_runtime.h>
#include <hip/hip_bf16.h>
#include <cstdint>

#define BB 2
#define SS 2048
#define DD 1024
#define HH 16
#define DK 64
#define MROWS (BB*SS)        // 4096
#define NQKV  (3*DD)         // 3072

typedef __bf16 bf16x8 __attribute__((ext_vector_type(8)));
typedef float  f32x4  __attribute__((ext_vector_type(4)));
typedef float  f32x16 __attribute__((ext_vector_type(16)));
typedef unsigned u32x2 __attribute__((ext_vector_type(2)));

static __device__ __forceinline__ unsigned short f2bf(float f) {
    __bf16 h = (__bf16)f;
    return __builtin_bit_cast(unsigned short, h);
}
static __device__ __forceinline__ float bf2f(unsigned short u) {
    return (float)__builtin_bit_cast(__bf16, u);
}

#define GLOAD16(gsrc, ldst) \
    __builtin_amdgcn_global_load_lds((const __attribute__((address_space(1))) void*)(gsrc), \
                                     (__attribute__((address_space(3))) void*)(ldst), 16, 0, 0)

// v_permlane32_swap_b32: first operand's HIGH half swaps with second operand's LOW half.
static __device__ __forceinline__ void pl32_swap(unsigned &x, unsigned &y) {
#if __has_builtin(__builtin_amdgcn_permlane32_swap)
    u32x2 r = __builtin_amdgcn_permlane32_swap(x, y, false, false);
    x = r[0]; y = r[1];
#else
    asm volatile("v_permlane32_swap_b32 %0, %1" : "+v"(x), "+v"(y));
#endif
}
static __device__ __forceinline__ float swap_half(float v, bool hi) {
    unsigned x = __builtin_bit_cast(unsigned, v), y = x;
    pl32_swap(x, y);
    return __builtin_bit_cast(float, hi ? x : y);
}
// T12: build PV B-frag from 8 f32 C-layout regs (verified R10).
template<int BASE> static __device__ __forceinline__ bf16x8 cvt_chunk(const f32x16 &p) {
    unsigned x0, y0, x1, y1;
    asm("v_cvt_pk_bf16_f32 %0, %1, %2" : "=v"(x0) : "v"(p[BASE+0]), "v"(p[BASE+1]));
    asm("v_cvt_pk_bf16_f32 %0, %1, %2" : "=v"(y0) : "v"(p[BASE+4]), "v"(p[BASE+5]));
    asm("v_cvt_pk_bf16_f32 %0, %1, %2" : "=v"(x1) : "v"(p[BASE+2]), "v"(p[BASE+3]));
    asm("v_cvt_pk_bf16_f32 %0, %1, %2" : "=v"(y1) : "v"(p[BASE+6]), "v"(p[BASE+7]));
    pl32_swap(x0, y0);
    pl32_swap(x1, y1);
    union { unsigned u[4]; bf16x8 v; } r;
    r.u[0] = x0; r.u[1] = x1; r.u[2] = y0; r.u[3] = y1;
    return r.v;
}

// ---------------------------------------------------------------- cast x + weights to bf16
__global__ void cast_all(const float* __restrict__ x,  const float* __restrict__ wq,
                         const float* __restrict__ wk, const float* __restrict__ wv,
                         const float* __restrict__ wo,
                         unsigned short* __restrict__ xb, unsigned short* __restrict__ wqkv,
                         unsigned short* __restrict__ wob)
{
    const int NX = MROWS * DD;      // 4194304
    const int NW = DD * DD;         // 1048576
    const int total = (NX + 4 * NW) / 8;
    for (int i = blockIdx.x * blockDim.x + threadIdx.x; i < total; i += gridDim.x * blockDim.x) {
        int base = i * 8;
        const float* src; unsigned short* dst; int off;
        if      (base < NX)          { src = x;  dst = xb;          off = base; }
        else if (base < NX + NW)     { src = wq; dst = wqkv;        off = base - NX; }
        else if (base < NX + 2*NW)   { src = wk; dst = wqkv + NW;   off = base - NX - NW; }
        else if (base < NX + 3*NW)   { src = wv; dst = wqkv + 2*NW; off = base - NX - 2*NW; }
        else                         { src = wo; dst = wob;         off = base - NX - 3*NW; }
        float4 a = *(const float4*)(src + off);
        float4 b = *(const float4*)(src + off + 4);
        union { unsigned short s[8]; uint4 v; } u;
        u.s[0] = f2bf(a.x); u.s[1] = f2bf(a.y); u.s[2] = f2bf(a.z); u.s[3] = f2bf(a.w);
        u.s[4] = f2bf(b.x); u.s[5] = f2bf(b.y); u.s[6] = f2bf(b.z); u.s[7] = f2bf(b.w);
        *(uint4*)(dst + off) = u.v;
    }
}

// ---------------------------------------------------------------- RoPE cos/sin table [2048][32]
__global__ void rope_table(float* __restrict__ tabc, float* __restrict__ tabs)
{
    int i = blockIdx.x * blockDim.x + threadIdx.x;   // 65536 threads
    int s = i >> 5, d = i & 31;
    float inv = exp2f(-(float)d * (13.287712379549449f / 32.f));  // 10000^(-d/32)
    float ang = (float)s * inv;
    tabc[i] = cosf(ang);
    tabs[i] = sinf(ang);
}

// ---------------------------------------------------------------- fused QKV GEMM + RoPE epilogue
// FULL-FILL variant: BM=256, BN=192, 6 waves (2Mx3N, 384 thr), grid 16x16 = 256 blocks
// = exactly 1/CU (prior 256x256 config filled only 192/256 CUs). Same per-wave 128x64
// tile, same m201-order phase schedule, same XOR swizzle. LDS (256+192)*64*2*2 = 112KB.
// Every wave's 64-col span is region/head-aligned (192*bx + 64*wn, boundaries at 1024/
// 2048 are 64-multiples) -> per-wave Q/K/V epilogue dispatch; RoPE pairs stay in-span.
__global__ __launch_bounds__(384) void gemm_qkv(
    const unsigned short* __restrict__ A, const unsigned short* __restrict__ Bm,
    const int* __restrict__ pids,
    const float* __restrict__ tabc, const float* __restrict__ tabs,
    unsigned short* __restrict__ Qb, unsigned short* __restrict__ Kb,
    unsigned short* __restrict__ Vr)
{
    __shared__ __align__(16) unsigned short sA[2][16384];   // [256][64] per buf (32KB)
    __shared__ __align__(16) unsigned short sB[2][12288];   // [192][64] per buf (24KB)
    const int tid = threadIdx.x;
    const int w = tid / 64, l = tid & 63;
    const int wm = w / 3, wn = w % 3;        // 2M x 3N wave grid
    const int lr = l & 15, lg = l >> 4;
    // XCD swizzle: 256 blocks = 8 XCDs x 32 (bijective)
    const int swz = (blockIdx.x & 7) * 32 + (blockIdx.x >> 3);
    const int bx = swz & 15, by = swz >> 4;
    const int mBase = by * 256;
    const int nBase = bx * 192;
    const int rdsw = (lr & 7) * 8;           // read-side XOR term

    f32x4 acc[8][4] = {};

    // stage K-tile kt into buf bb: flat index over A (2048 loads) then B (1536 loads);
    // 3584 loads / 384 thr = 10 rounds (last partial; spans are 64-aligned -> wave-uniform).
    // Per-lane LDS dest = wave base + lane*16B (R22-verified pattern); source col XOR-swizzled.
    auto stage = [&](int kt, int bb) {
        #pragma unroll
        for (int r = 0; r < 10; ++r) {
            int idx = tid + r * 384;
            if (idx < 2048) {
                int row = idx >> 3, ch = idx & 7;
                GLOAD16(A + (size_t)(mBase + row) * DD + kt + ((ch ^ (row & 7)) * 8),
                        &sA[bb][idx * 8]);
            } else if (idx < 3584) {
                int i2 = idx - 2048;
                int row = i2 >> 3, ch = i2 & 7;
                GLOAD16(Bm + (size_t)(nBase + row) * DD + kt + ((ch ^ (row & 7)) * 8),
                        &sB[bb][i2 * 8]);
            }
        }
    };

    stage(0, 0);
    __syncthreads();   // drain: tile 0 staged

    for (int t = 0; t < 16; ++t) {
        const int cur = t & 1;
        #pragma unroll
        for (int p = 0; p < 4; ++p) {
            const int rh = p & 1, ks = p >> 1;
            bf16x8 af[4], bfv[4];
            #pragma unroll
            for (int rf = 0; rf < 4; ++rf) {
                int ra = wm*128 + rh*64 + rf*16 + lr;
                af[rf] = *(const bf16x8*)&sA[cur][ra*64 + ((ks*32 + lg*8) ^ rdsw)];
            }
            #pragma unroll
            for (int cf = 0; cf < 4; ++cf) {
                int rb = wn*64 + cf*16 + lr;
                bfv[cf] = *(const bf16x8*)&sB[cur][rb*64 + ((ks*32 + lg*8) ^ rdsw)];
            }
            if (p == 0 && t < 15) stage((t+1)*64, cur ^ 1);   // prefetch next tile
            __builtin_amdgcn_s_barrier();                      // align waves; loads in flight
            __builtin_amdgcn_s_setprio(1);
            #pragma unroll
            for (int rf = 0; rf < 4; ++rf)
                #pragma unroll
                for (int cf = 0; cf < 4; ++cf)
                    acc[rh*4+rf][cf] = __builtin_amdgcn_mfma_f32_16x16x32_bf16(
                        af[rf], bfv[cf], acc[rh*4+rf][cf], 0, 0, 0);
            __builtin_amdgcn_s_setprio(0);
            if (p < 3) __builtin_amdgcn_s_barrier();
        }
        __syncthreads();   // drains vmcnt: buf[cur^1] fully staged; all waves done with buf[cur]
    }

    // ---- epilogue: per-wave region dispatch (wave col span = one head slice)
    const int gcol = nBase + wn*64;          // 64-aligned global column of this wave
    const int region = gcol >> 10;           // 0=Q, 1=K, 2=V
    const int hcol = gcol & 1023;            // head-aligned column within region
    if (region < 2) {
        unsigned short* dst = (region == 0) ? Qb : Kb;
        const float qsc = (region == 0) ? 0.1803368801111244f : 1.0f;   // 0.125*log2e on Q
        #pragma unroll
        for (int rr = 0; rr < 8; ++rr) {
            #pragma unroll
            for (int j = 0; j < 4; ++j) {
                int row = mBase + wm*128 + rr*16 + lg*4 + j;
                int pos = pids[row];
                #pragma unroll
                for (int cf = 0; cf < 2; ++cf) {
                    int d = cf*16 + lr;                        // 0..31
                    float cc = tabc[pos*32 + d];
                    float sn = tabs[pos*32 + d];
                    float a  = acc[rr][cf][j];
                    float bb2 = acc[rr][cf+2][j];
                    dst[(size_t)row * DD + hcol + d]      = f2bf((a*cc - bb2*sn) * qsc);
                    dst[(size_t)row * DD + hcol + d + 32] = f2bf((bb2*cc + a*sn) * qsc);
                }
            }
        }
    } else {
        #pragma unroll
        for (int rr = 0; rr < 8; ++rr) {
            #pragma unroll
            for (int j = 0; j < 4; ++j) {
                int row = mBase + wm*128 + rr*16 + lg*4 + j;
                #pragma unroll
                for (int cf = 0; cf < 4; ++cf)
                    Vr[(size_t)row * DD + hcol + cf*16 + lr] = f2bf(acc[rr][cf][j]);
            }
        }
    }
}

// ---------------------------------------------------------------- out-proj GEMM + bias
// T3-min dbuf (R12/R14 structure): 256 blocks = 1 block/CU.
__global__ __launch_bounds__(256) void gemm_bt(
    const unsigned short* __restrict__ A, const unsigned short* __restrict__ Bm,
    float* __restrict__ Cout, const float* __restrict__ bias,
    int M, int N, int K)
{
    __shared__ __align__(16) unsigned short sA[2][128 * 64];
    __shared__ __align__(16) unsigned short sB[2][128 * 64];
    const int tid = threadIdx.x;
    const int w = tid >> 6, l = tid & 63;
    const int wm = w >> 1, wn = w & 1;
    const int lr = l & 15, lg = l >> 4;
    const int nwg = gridDim.x;
    const int cpx = nwg >> 3;
    const int swz = (blockIdx.x & 7) * cpx + (blockIdx.x >> 3);
    const int nbx = N >> 7;
    const int bx = swz % nbx, by = swz / nbx;
    const int mBase = by * 128, nBase = bx * 128;
    const int srow = tid >> 3;
    const int skof = (tid & 7) * 8;

    f32x4 acc[4][4] = {};

    #pragma unroll
    for (int i = 0; i < 4; ++i) {
        GLOAD16(A  + (size_t)(mBase + i*32 + srow) * K + skof, &sA[0][i*2048 + w*512]);
        GLOAD16(Bm + (size_t)(nBase + i*32 + srow) * K + skof, &sB[0][i*2048 + w*512]);
    }
    int cur = 0;

    for (int kt = 0; kt < K; kt += 64) {
        __syncthreads();
        if (kt + 64 < K) {
            #pragma unroll
            for (int i = 0; i < 4; ++i) {
                GLOAD16(A  + (size_t)(mBase + i*32 + srow) * K + kt + 64 + skof, &sA[cur^1][i*2048 + w*512]);
                GLOAD16(Bm + (size_t)(nBase + i*32 + srow) * K + kt + 64 + skof, &sB[cur^1][i*2048 + w*512]);
            }
        }
        #pragma unroll
        for (int kk = 0; kk < 2; ++kk) {
            bf16x8 af[4], bfv[4];
            #pragma unroll
            for (int mi = 0; mi < 4; ++mi)
                af[mi] = *(const bf16x8*)&sA[cur][(wm*64 + mi*16 + lr)*64 + kk*32 + lg*8];
            #pragma unroll
            for (int ni = 0; ni < 4; ++ni)
                bfv[ni] = *(const bf16x8*)&sB[cur][(wn*64 + ni*16 + lr)*64 + kk*32 + lg*8];
            #pragma unroll
            for (int mi = 0; mi < 4; ++mi)
                #pragma unroll
                for (int ni = 0; ni < 4; ++ni)
                    acc[mi][ni] = __builtin_amdgcn_mfma_f32_16x16x32_bf16(af[mi], bfv[ni], acc[mi][ni], 0, 0, 0);
        }
        cur ^= 1;
    }
    #pragma unroll
    for (int mi = 0; mi < 4; ++mi) {
        #pragma unroll
        for (int j = 0; j < 4; ++j) {
            int row = mBase + wm*64 + mi*16 + lg*4 + j;
            #pragma unroll
            for (int ni = 0; ni < 4; ++ni) {
                int col = nBase + wn*64 + ni*16 + lr;
                Cout[(size_t)row * N + col] = acc[mi][ni][j] + bias[col];
            }
        }
    }
}

// ---------------------------------------------------------------- V transpose via chunk-swizzled LDS tile
// Vr [4096][1024] -> Vt [32*64][2048]
__global__ __launch_bounds__(256) void v_transpose(
    const unsigned short* __restrict__ Vr, unsigned short* __restrict__ Vt)
{
    __shared__ __align__(16) unsigned short sT[64 * 64];
    const int bh = blockIdx.y;          // 0..31
    const int st = blockIdx.x;          // 0..31 (s-tile)
    const int b = bh >> 4, h = bh & 15;
    const int tid = threadIdx.x;
    #pragma unroll
    for (int i = 0; i < 2; ++i) {
        int c = tid + i*256;            // chunk 0..511
        int s = c >> 3, cb = c & 7;
        const unsigned short* src = Vr + (size_t)(b*SS + st*64 + s) * DD + h*64 + cb*8;
        uint4 v = *(const uint4*)src;
        *(uint4*)&sT[s*64 + ((cb ^ (s >> 3)) * 8)] = v;   // chunk-swizzled store
    }
    __syncthreads();
    #pragma unroll
    for (int i = 0; i < 2; ++i) {
        int c = tid + i*256;
        int d = c >> 3, sb = c & 7;
        union { unsigned short u[8]; uint4 v; } o;
        #pragma unroll
        for (int e = 0; e < 8; ++e) {
            int s = sb*8 + e;
            o.u[e] = sT[s*64 + (((d >> 3) ^ (s >> 3)) * 8) + (d & 7)];
        }
        *(uint4*)(Vt + (size_t)(bh*64 + d) * SS + st*64 + sb*8) = o.v;
    }
}

// ---------------------------------------------------------------- flash attention fwd (causal)
// R20 structure: T12, 4 waves x 32 q-rows = 128-row q-tile, KVBLK=128 LDS staging,
// QK for both sub-steps up front.
__global__ __launch_bounds__(256, 2) void attn_fwd(
    const unsigned short* __restrict__ Qb,   // [4096][1024], pre-scaled by 0.125*log2e
    const unsigned short* __restrict__ Kb,   // [4096][1024]
    const unsigned short* __restrict__ Vt,   // [2048][2048]
    unsigned short* __restrict__ Ob)         // [4096][1024]
{
    __shared__ __align__(16) unsigned short sK[2][8192];   // [128 k-rows][64 d], 16KB/buf
    __shared__ __align__(16) unsigned short sV[2][8192];   // 2 panels of [64 d][64 s]
    const int tid = threadIdx.x;
    const int w = tid >> 6, l = tid & 63;
    const int lq = l & 31;
    const int hi5 = l >> 5;
    const bool hb = hi5 != 0;

    const int xcd  = blockIdx.x & 7;
    const int c    = blockIdx.x >> 3;        // 0..63
    const int gsel = c & 3;
    const int t    = c >> 2;                 // 0..15
    const int qt   = (t < 8) ? t : 23 - t;   // 128-row q-tile index 0..15
    const int bh   = xcd * 4 + gsel;
    const int b = bh >> 4, h = bh & 15;

    const int srow = tid >> 3;               // 0..31
    const int skof = (tid & 7) * 8;
    const int sksw = skof ^ ((srow & 7) * 8);   // pre-swizzled staging col (elements)
    const int sw   = (lq & 7) * 8;              // read-side XOR term
    const float THR = 12.0f;

    // Q fragments: Q[q = qt*128 + w*32 + lq][dk = dkc*16 + hi5*8 + e]
    bf16x8 qf[4];
    {
        const unsigned short* qp = Qb + (size_t)(b*SS + qt*128 + w*32 + lq) * DD + h*64 + hi5*8;
        #pragma unroll
        for (int dkc = 0; dkc < 4; ++dkc)
            qf[dkc] = *(const bf16x8*)(qp + dkc*16);
    }
    const int q_lane = qt*128 + w*32 + lq;
    const int wbase  = qt*128 + w*32;        // wave's min q-row (mask gate)

    f32x16 o0 = {}, o1 = {};
    float mrow = -3.0e38f, lsum = 0.f;
    int cur = 0;

    // stage 128-wide kv-tile ktt into buf bb
    auto stage = [&](int ktt, int bb) {
        #pragma unroll
        for (int r = 0; r < 4; ++r)
            GLOAD16(Kb + (size_t)(b*SS + ktt*128 + r*32 + srow) * DD + h*64 + sksw,
                    &sK[bb][r*2048 + w*512]);
        #pragma unroll
        for (int s = 0; s < 2; ++s)
            #pragma unroll
            for (int r = 0; r < 2; ++r)
                GLOAD16(Vt + (size_t)(bh*64 + r*32 + srow) * SS + ktt*128 + s*64 + sksw,
                        &sV[bb][s*4096 + r*2048 + w*512]);
    };

    stage(0, 0);

    for (int ktt = 0; ktt <= qt; ++ktt) {
        __syncthreads();   // vmcnt drained: buf[cur] staged; all waves done with buf[cur^1]
        if (ktt < qt) stage(ktt + 1, cur ^ 1);

        // ---- QK^T for BOTH sub-steps up front (independent MFMA batches)
        f32x16 pa0 = {}, pa1 = {};   // sub-step 0
        f32x16 pb0 = {}, pb1 = {};   // sub-step 1
        __builtin_amdgcn_s_setprio(1);
        #pragma unroll
        for (int dkc = 0; dkc < 4; ++dkc) {
            bf16x8 k0 = *(const bf16x8*)&sK[cur][lq*64 + ((dkc*16 + hi5*8) ^ sw)];
            pa0 = __builtin_amdgcn_mfma_f32_32x32x16_bf16(k0, qf[dkc], pa0, 0, 0, 0);
        }
        #pragma unroll
        for (int dkc = 0; dkc < 4; ++dkc) {
            bf16x8 k1 = *(const bf16x8*)&sK[cur][2048 + lq*64 + ((dkc*16 + hi5*8) ^ sw)];
            pa1 = __builtin_amdgcn_mfma_f32_32x32x16_bf16(k1, qf[dkc], pa1, 0, 0, 0);
        }
        #pragma unroll
        for (int dkc = 0; dkc < 4; ++dkc) {
            bf16x8 k2 = *(const bf16x8*)&sK[cur][4096 + lq*64 + ((dkc*16 + hi5*8) ^ sw)];
            pb0 = __builtin_amdgcn_mfma_f32_32x32x16_bf16(k2, qf[dkc], pb0, 0, 0, 0);
        }
        #pragma unroll
        for (int dkc = 0; dkc < 4; ++dkc) {
            bf16x8 k3 = *(const bf16x8*)&sK[cur][4096 + 2048 + lq*64 + ((dkc*16 + hi5*8) ^ sw)];
            pb1 = __builtin_amdgcn_mfma_f32_32x32x16_bf16(k3, qf[dkc], pb1, 0, 0, 0);
        }
        __builtin_amdgcn_s_setprio(0);

        // ---- SM0 — sub-step kt = 2ktt
        {
            const int kt = 2*ktt;
            if (kt*64 + 63 > wbase) {
                const int kb0 = kt*64 + 4*hi5;
                #pragma unroll
                for (int r = 0; r < 16; ++r) {
                    const int cr = (r & 3) + 8*(r >> 2);
                    if (kb0 + cr > q_lane)      pa0[r] = -1e30f;
                    if (kb0 + 32 + cr > q_lane) pa1[r] = -1e30f;
                }
            }
            float tt[16];
            #pragma unroll
            for (int r = 0; r < 16; ++r) tt[r] = fmaxf(pa0[r], pa1[r]);
            #pragma unroll
            for (int s2 = 8; s2 >= 1; s2 >>= 1)
                #pragma unroll
                for (int r = 0; r < 8; ++r)
                    if (r < s2) tt[r] = fmaxf(tt[r], tt[r + s2]);
            float tmx = fmaxf(tt[0], swap_half(tt[0], hb));
            float growth = tmx - mrow;
            if (!__all(growth <= THR)) {
                float mnew = fmaxf(mrow, tmx);
                float alpha = exp2f(mrow - mnew);
                lsum *= alpha;
                mrow = mnew;
                #pragma unroll
                for (int r = 0; r < 16; ++r) { o0[r] *= alpha; o1[r] *= alpha; }
            }
            #pragma unroll
            for (int r = 0; r < 16; ++r) {
                pa0[r] = exp2f(pa0[r] - mrow);
                pa1[r] = exp2f(pa1[r] - mrow);
            }
            float st[16];
            #pragma unroll
            for (int r = 0; r < 16; ++r) st[r] = pa0[r] + pa1[r];
            #pragma unroll
            for (int s2 = 8; s2 >= 1; s2 >>= 1)
                #pragma unroll
                for (int r = 0; r < 8; ++r)
                    if (r < s2) st[r] += st[r + s2];
            lsum += st[0];
        }

        // ---- PV0
        __builtin_amdgcn_s_setprio(1);
        {
            bf16x8 pv, vf;
            pv = cvt_chunk<0>(pa0);
            vf = *(const bf16x8*)&sV[cur][lq*64 + ((0*16 + hi5*8) ^ sw)];
            o0 = __builtin_amdgcn_mfma_f32_32x32x16_bf16(vf, pv, o0, 0, 0, 0);
            vf = *(const bf16x8*)&sV[cur][2048 + lq*64 + ((0*16 + hi5*8) ^ sw)];
            o1 = __builtin_amdgcn_mfma_f32_32x32x16_bf16(vf, pv, o1, 0, 0, 0);
            pv = cvt_chunk<8>(pa0);
            vf = *(const bf16x8*)&sV[cur][lq*64 + ((1*16 + hi5*8) ^ sw)];
            o0 = __builtin_amdgcn_mfma_f32_32x32x16_bf16(vf, pv, o0, 0, 0, 0);
            vf = *(const bf16x8*)&sV[cur][2048 + lq*64 + ((1*16 + hi5*8) ^ sw)];
            o1 = __builtin_amdgcn_mfma_f32_32x32x16_bf16(vf, pv, o1, 0, 0, 0);
            pv = cvt_chunk<0>(pa1);
            vf = *(const bf16x8*)&sV[cur][lq*64 + ((2*16 + hi5*8) ^ sw)];
            o0 = __builtin_amdgcn_mfma_f32_32x32x16_bf16(vf, pv, o0, 0, 0, 0);
            vf = *(const bf16x8*)&sV[cur][2048 + lq*64 + ((2*16 + hi5*8) ^ sw)];
            o1 = __builtin_amdgcn_mfma_f32_32x32x16_bf16(vf, pv, o1, 0, 0, 0);
            pv = cvt_chunk<8>(pa1);
            vf = *(const bf16x8*)&sV[cur][lq*64 + ((3*16 + hi5*8) ^ sw)];
            o0 = __builtin_amdgcn_mfma_f32_32x32x16_bf16(vf, pv, o0, 0, 0, 0);
            vf = *(const bf16x8*)&sV[cur][2048 + lq*64 + ((3*16 + hi5*8) ^ sw)];
            o1 = __builtin_amdgcn_mfma_f32_32x32x16_bf16(vf, pv, o1, 0, 0, 0);
        }
        __builtin_amdgcn_s_setprio(0);

        // ---- SM1 — sub-step kt = 2ktt+1
        {
            const int kt = 2*ktt + 1;
            if (kt*64 + 63 > wbase) {
                const int kb0 = kt*64 + 4*hi5;
                #pragma unroll
                for (int r = 0; r < 16; ++r) {
                    const int cr = (r & 3) + 8*(r >> 2);
                    if (kb0 + cr > q_lane)      pb0[r] = -1e30f;
                    if (kb0 + 32 + cr > q_lane) pb1[r] = -1e30f;
                }
            }
            float tt[16];
            #pragma unroll
            for (int r = 0; r < 16; ++r) tt[r] = fmaxf(pb0[r], pb1[r]);
            #pragma unroll
            for (int s2 = 8; s2 >= 1; s2 >>= 1)
                #pragma unroll
                for (int r = 0; r < 8; ++r)
                    if (r < s2) tt[r] = fmaxf(tt[r], tt[r + s2]);
            float tmx = fmaxf(tt[0], swap_half(tt[0], hb));
            float growth = tmx - mrow;
            if (!__all(growth <= THR)) {
                float mnew = fmaxf(mrow, tmx);
                float alpha = exp2f(mrow - mnew);
                lsum *= alpha;
                mrow = mnew;
                #pragma unroll
                for (int r = 0; r < 16; ++r) { o0[r] *= alpha; o1[r] *= alpha; }
            }
            #pragma unroll
            for (int r = 0; r < 16; ++r) {
                pb0[r] = exp2f(pb0[r] - mrow);
                pb1[r] = exp2f(pb1[r] - mrow);
            }
            float st[16];
            #pragma unroll
            for (int r = 0; r < 16; ++r) st[r] = pb0[r] + pb1[r];
            #pragma unroll
            for (int s2 = 8; s2 >= 1; s2 >>= 1)
                #pragma unroll
                for (int r = 0; r < 8; ++r)
                    if (r < s2) st[r] += st[r + s2];
            lsum += st[0];
        }

        // ---- PV1
        __builtin_amdgcn_s_setprio(1);
        {
            bf16x8 pv, vf;
            pv = cvt_chunk<0>(pb0);
            vf = *(const bf16x8*)&sV[cur][4096 + lq*64 + ((0*16 + hi5*8) ^ sw)];
            o0 = __builtin_amdgcn_mfma_f32_32x32x16_bf16(vf, pv, o0, 0, 0, 0);
            vf = *(const bf16x8*)&sV[cur][4096 + 2048 + lq*64 + ((0*16 + hi5*8) ^ sw)];
            o1 = __builtin_amdgcn_mfma_f32_32x32x16_bf16(vf, pv, o1, 0, 0, 0);
            pv = cvt_chunk<8>(pb0);
            vf = *(const bf16x8*)&sV[cur][4096 + lq*64 + ((1*16 + hi5*8) ^ sw)];
            o0 = __builtin_amdgcn_mfma_f32_32x32x16_bf16(vf, pv, o0, 0, 0, 0);
            vf = *(const bf16x8*)&sV[cur][4096 + 2048 + lq*64 + ((1*16 + hi5*8) ^ sw)];
            o1 = __builtin_amdgcn_mfma_f32_32x32x16_bf16(vf, pv, o1, 0, 0, 0);
            pv = cvt_chunk<0>(pb1);
            vf = *(const bf16x8*)&sV[cur][4096 + lq*64 + ((2*16 + hi5*8) ^ sw)];
            o0 = __builtin_amdgcn_mfma_f32_32x32x16_bf16(vf, pv, o0, 0, 0, 0);
            vf = *(const bf16x8*)&sV[cur][4096 + 2048 + lq*64 + ((2*16 + hi5*8) ^ sw)];
            o1 = __builtin_amdgcn_mfma_f32_32x32x16_bf16(vf, pv, o1, 0, 0, 0);
            pv = cvt_chunk<8>(pb1);
            vf = *(const bf16x8*)&sV[cur][4096 + lq*64 + ((3*16 + hi5*8) ^ sw)];
            o0 = __builtin_amdgcn_mfma_f32_32x32x16_bf16(vf, pv, o0, 0, 0, 0);
            vf = *(const bf16x8*)&sV[cur][4096 + 2048 + lq*64 + ((3*16 + hi5*8) ^ sw)];
            o1 = __builtin_amdgcn_mfma_f32_32x32x16_bf16(vf, pv, o1, 0, 0, 0);
        }
        __builtin_amdgcn_s_setprio(0);
        cur ^= 1;
    }

    // ---- epilogue: normalize, LDS-transpose O (reuse sK, barrier first), coalesced store
    __syncthreads();
    float ls = lsum + swap_half(lsum, hb);
    float inv = 1.f / ls;
    unsigned short* sOw = &sK[0][0] + w * 2048;   // per-wave [32 q][64 d] bf16

    #pragma unroll
    for (int g2 = 0; g2 < 4; ++g2) {
        unsigned ua, ub; uint2 t2;
        float v0 = o0[g2*4+0]*inv, v1 = o0[g2*4+1]*inv, v2 = o0[g2*4+2]*inv, v3 = o0[g2*4+3]*inv;
        asm("v_cvt_pk_bf16_f32 %0, %1, %2" : "=v"(ua) : "v"(v0), "v"(v1));
        asm("v_cvt_pk_bf16_f32 %0, %1, %2" : "=v"(ub) : "v"(v2), "v"(v3));
        t2.x = ua; t2.y = ub;
        *(uint2*)&sOw[lq*64 + g2*8 + hi5*4] = t2;
        float w0 = o1[g2*4+0]*inv, w1 = o1[g2*4+1]*inv, w2 = o1[g2*4+2]*inv, w3 = o1[g2*4+3]*inv;
        asm("v_cvt_pk_bf16_f32 %0, %1, %2" : "=v"(ua) : "v"(w0), "v"(w1));
        asm("v_cvt_pk_bf16_f32 %0, %1, %2" : "=v"(ub) : "v"(w2), "v"(w3));
        t2.x = ua; t2.y = ub;
        *(uint2*)&sOw[lq*64 + 32 + g2*8 + hi5*4] = t2;
    }
    asm volatile("s_waitcnt lgkmcnt(0)" ::: "memory");
    __builtin_amdgcn_sched_barrier(0);

    const int row = l >> 1, cb2 = (l & 1) * 32;
    const unsigned short* sOr = sOw + row*64 + cb2;
    unsigned short* gp = Ob + (size_t)(b*SS + qt*128 + w*32 + row) * DD + h*64 + cb2;
    #pragma unroll
    for (int c2 = 0; c2 < 4; ++c2)
        *(uint4*)(gp + c2*8) = *(const uint4*)(sOr + c2*8);
}

// ---------------------------------------------------------------- launch
extern "C" void kernel_launch(void* const* d_in, const int* in_sizes, int n_in,
                              void* d_out, int out_size, void* d_ws, size_t ws_size,
                              hipStream_t stream)
{
    const float* x  = (const float*)d_in[0];
    // d_in[1] = mask (causal tril; implemented analytically)
    const int* pids = (const int*)d_in[2];
    const float* wq = (const float*)d_in[3];
    const float* wk = (const float*)d_in[4];
    const float* wv = (const float*)d_in[5];
    const float* wo = (const float*)d_in[6];
    const float* bo = (const float*)d_in[7];
    float* out = (float*)d_out;

    char* ws = (char*)d_ws;
    unsigned short* xb   = (unsigned short*)(ws);                        // 8 MB
    unsigned short* wqkv = (unsigned short*)(ws + (size_t)( 8u<<20));    // 6 MB
    unsigned short* wob  = (unsigned short*)(ws + (size_t)(14u<<20));    // 2 MB
    unsigned short* Vr   = (unsigned short*)(ws + (size_t)(16u<<20));    // 8 MB
    unsigned short* Qb   = (unsigned short*)(ws + (size_t)(40u<<20));    // 8 MB
    unsigned short* Kb   = (unsigned short*)(ws + (size_t)(48u<<20));    // 8 MB
    unsigned short* Vt   = (unsigned short*)(ws + (size_t)(56u<<20));    // 8 MB
    float* tabc          = (float*)(ws + (size_t)(64u<<20));             // 256 KB
    float* tabs          = (float*)(ws + (size_t)(64u<<20) + (256u<<10));// 256 KB
    unsigned short* Ob   = xb;  // alias: x_bf16 dead after QKV GEMM

    cast_all<<<dim3(4096), dim3(256), 0, stream>>>(x, wq, wk, wv, wo, xb, wqkv, wob);
    rope_table<<<dim3(256), dim3(256), 0, stream>>>(tabc, tabs);
    gemm_qkv<<<dim3(256), dim3(384), 0, stream>>>(
        xb, wqkv, pids, tabc, tabs, Qb, Kb, Vr);
    v_transpose<<<dim3(32, 32), dim3(256), 0, stream>>>(Vr, Vt);
    attn_fwd<<<dim3(512), dim3(256), 0, stream>>>(Qb, Kb, Vt, Ob);
    gemm_bt<<<dim3(256), dim3(256), 0, stream>>>(
        Ob, wob, out, bo, MROWS, DD, DD);
}